// Round 10
// baseline (249.188 us; speedup 1.0000x reference)
//
#include <hip/hip_runtime.h>
#include <math.h>

#define BB 32
#define NN 128
#define DD 64
#define EE (NN*NN)          // 16384
#define EPSI 1e-5f

typedef __attribute__((ext_vector_type(8))) short bf16x8;   // 8 bf16 (4 VGPRs)
typedef __attribute__((ext_vector_type(4))) float f32x4;

// lgkmcnt(0)-only wait (NOT s_waitcnt 0: that drains vmcnt too -> store stalls)
#define LGKM0() do { asm volatile("s_waitcnt lgkmcnt(0)" ::: "memory"); \
                     __builtin_amdgcn_sched_barrier(0); } while (0)
#define VM0()   do { asm volatile("s_waitcnt vmcnt(0)" ::: "memory"); \
                     __builtin_amdgcn_sched_barrier(0); } while (0)

__device__ __forceinline__ short f2bf(float f) {
    union { float f; unsigned u; } v; v.f = f;
    unsigned u = v.u;
    unsigned r = (u + 0x7FFFu + ((u >> 16) & 1u)) >> 16;    // RNE
    return (short)r;
}
__device__ __forceinline__ float bf2f(short s) {
    union { unsigned u; float f; } v; v.u = ((unsigned)(unsigned short)s) << 16;
    return v.f;
}
__device__ __forceinline__ float elu(float v) {
    return v > 0.f ? v : __expf(v) - 1.f;     // v_exp_f32 path
}

// ---------------------------------------------------------------------------
// k_node (+ folded k_fold): blocks [0, B*N): per (b,n) row:
//   z_h = x @ Wh^T ; PsT/PdT in MFMA C-fragment layout ; s,t scalars.
// blocks [B*N, B*N+64): fold — Mbf[d][k] = bf16(sum_o Wp[d][128+o]*We[o][k]),
//   block ff==0 also wf32[k] = sum_o Wa[128+o]*We[o][k].
__global__ void k_node(const float* __restrict__ x, const float* __restrict__ Wh,
                       const float* __restrict__ Wp, const float* __restrict__ We,
                       const float* __restrict__ Wa,
                       float* __restrict__ zh, float* __restrict__ PsT,
                       float* __restrict__ PdT, float* __restrict__ sO,
                       float* __restrict__ tO,
                       short* __restrict__ Mbf, float* __restrict__ wf32)
{
    const int row = blockIdx.x;
    const int d = threadIdx.x;           // 0..63
    if (row >= BB*NN) {                  // ---- fold tail blocks ----
        const int ff = row - BB*NN;      // 0..63 == output row d'
        float acc = 0.f;
        for (int o = 0; o < DD; ++o)
            acc += Wp[ff*192 + 128 + o] * We[o*DD + d];
        Mbf[ff*DD + d] = f2bf(acc);
        if (ff == 0) {
            float aw = 0.f;
            for (int o = 0; o < DD; ++o)
                aw += Wa[128 + o] * We[o*DD + d];
            wf32[d] = aw;
        }
        return;
    }
    const int b = row >> 7, n = row & 127;
    __shared__ float xr[DD];
    __shared__ float zr[DD];
    xr[d] = x[row*DD + d];
    __syncthreads();
    float acc = 0.f;
#pragma unroll
    for (int k = 0; k < DD; ++k) acc += xr[k] * Wh[d*DD + k];
    zr[d] = acc;
    zh[row*DD + d] = acc;
    __syncthreads();
    float a0 = 0.f, a1 = 0.f;
#pragma unroll
    for (int o = 0; o < DD; ++o) {
        float z = zr[o];
        a0 += Wp[d*192 + o]      * z;
        a1 += Wp[d*192 + 64 + o] * z;
    }
    const int fi = ((b >> 4)*4 + (d >> 4))*256 + (((b >> 2) & 3)*16 + (d & 15))*4 + (b & 3);
    PsT[n*2048 + fi] = a0;
    PdT[n*2048 + fi] = a1;
    float sv = zr[d] * Wa[d];
    float tv = zr[d] * Wa[64 + d];
#pragma unroll
    for (int off = 32; off; off >>= 1) {
        sv += __shfl_xor(sv, off);
        tv += __shfl_xor(tv, off);
    }
    if (d == 0) { sO[row] = sv; tO[row] = tv; }
}

// ---------------------------------------------------------------------------
// k_edge v10: 4 channels/block (4 waves, 1 ch/wave), async LDS staging.
//   z = edge @ M^T + Ps[b,j] + Pd[b,i] -> BN(per-e over b,d) -> ELU ; u = edge.w
// INM==0 (fp32 (B,E,D) input): rows (b, e0..e0+3) = contiguous 1KB runs staged
//   via global_load_lds (async, source-chunk-swizzled c^(b&7) so fragment
//   ds_read_b128 is conflict-free). u computed fp32 at LDS-read time.
// INM==1 (bf16 (E,B,D) dense): direct fragment loads; u from bf16 fragments.
// OUTM==0 (fp32 (B,E,D) d_out): fragments -> swizzled LDS chunks -> cooperative
//   1KB-contiguous float4 store bursts (dense writes).
// OUTM==1 (bf16 (E,B,D) dense): per-wave [32][68] repack -> 1KB bf16x8 bursts.
template <int INM, int OUTM>
__global__ __launch_bounds__(256, 4) void k_edge(
    const void* __restrict__ einv,
    const short* __restrict__ Mbf,   // (D,D) bf16
    const float* __restrict__ wf32,  // (D)   fp32
    const float* __restrict__ PsT,   // (N, 2048) fragment layout
    const float* __restrict__ PdT,   // (N, 2048) fragment layout
    const float* __restrict__ ge, const float* __restrict__ be,
    void* __restrict__ eoutv, float* __restrict__ uout)
{
    __shared__ float SA[8704];       // 34,816 B: stage [32][256] / repack overlay
    const int t  = threadIdx.x;
    const int l  = t & 63;
    const int wv = t >> 6;
    const int lr = l & 15;
    const int lg = l >> 4;
    const int e0 = blockIdx.x * 4;
    const int e  = e0 + wv;
    const int i0 = e0 >> 7;          // same node i for whole block (4 | 128)
    const int j0 = e & 127;

    // ---- async stage (INM==0): 8 x 1KB per wave, no VGPR round-trip ----
    if constexpr (INM == 0) {
        const float* ein = (const float*)einv;
#pragma unroll
        for (int r = 0; r < 8; ++r) {
            const int b = 8*wv + r;
            const float* gsrc = ein + ((size_t)b*EE + e0)*DD + ((l ^ (b & 7)) << 2);
            __builtin_amdgcn_global_load_lds(
                (const __attribute__((address_space(1))) unsigned*)gsrc,
                (__attribute__((address_space(3))) unsigned*)&SA[b*256], 16, 0, 0);
        }
    }

    // ---- B fragments (M^T bf16, L2-hot) + w regs ----
    bf16x8 bfr[4][2];
#pragma unroll
    for (int n = 0; n < 4; ++n)
#pragma unroll
        for (int s = 0; s < 2; ++s)
            bfr[n][s] = *reinterpret_cast<const bf16x8*>(Mbf + (16*n + lr)*DD + s*32 + lg*8);
    float4 wlo[2], whi[2];
#pragma unroll
    for (int s = 0; s < 2; ++s) {
        wlo[s] = *reinterpret_cast<const float4*>(wf32 + s*32 + lg*8);
        whi[s] = *reinterpret_cast<const float4*>(wf32 + s*32 + lg*8 + 4);
    }

    // ---- acc init = PsT[j0] + PdT[i0] (fragment-layout, L2-hot) ----
    f32x4 acc[2][4];
    {
        const float* psb = PsT + j0*2048;
        const float* pdb = PdT + i0*2048;
#pragma unroll
        for (int m = 0; m < 2; ++m)
#pragma unroll
            for (int n = 0; n < 4; ++n) {
                const float4 a = *reinterpret_cast<const float4*>(psb + (m*4+n)*256 + l*4);
                const float4 c = *reinterpret_cast<const float4*>(pdb + (m*4+n)*256 + l*4);
                acc[m][n] = (f32x4){a.x+c.x, a.y+c.y, a.z+c.z, a.w+c.w};
            }
    }

    // ---- A fragments (+u) ----
    bf16x8 afr[2][2];
    if constexpr (INM == 0) {
        VM0();
        __syncthreads();
#pragma unroll
        for (int m = 0; m < 2; ++m) {
            const int b = 16*m + lr;
            float up = 0.f;
#pragma unroll
            for (int s = 0; s < 2; ++s) {
                const int c = wv*16 + s*8 + lg*2;
                const f32x4 lo = *reinterpret_cast<const f32x4*>(&SA[b*256 + (( c    ^ (b&7)) << 2)]);
                const f32x4 hi = *reinterpret_cast<const f32x4*>(&SA[b*256 + (((c+1) ^ (b&7)) << 2)]);
                up += lo[0]*wlo[s].x + lo[1]*wlo[s].y + lo[2]*wlo[s].z + lo[3]*wlo[s].w
                    + hi[0]*whi[s].x + hi[1]*whi[s].y + hi[2]*whi[s].z + hi[3]*whi[s].w;
                bf16x8 a;
                a[0]=f2bf(lo[0]); a[1]=f2bf(lo[1]); a[2]=f2bf(lo[2]); a[3]=f2bf(lo[3]);
                a[4]=f2bf(hi[0]); a[5]=f2bf(hi[1]); a[6]=f2bf(hi[2]); a[7]=f2bf(hi[3]);
                afr[m][s] = a;
            }
            up += __shfl_xor(up, 16);
            up += __shfl_xor(up, 32);
            if (lg == 0) uout[(size_t)b*EE + e] = up;
        }
    } else {
        const short* ein = (const short*)einv + (size_t)e*BB*DD;
#pragma unroll
        for (int m = 0; m < 2; ++m)
#pragma unroll
            for (int s = 0; s < 2; ++s)
                afr[m][s] = *reinterpret_cast<const bf16x8*>(ein + (16*m + lr)*DD + s*32 + lg*8);
#pragma unroll
        for (int m = 0; m < 2; ++m) {
            float up = 0.f;
#pragma unroll
            for (int s = 0; s < 2; ++s) {
                up += bf2f(afr[m][s][0])*wlo[s].x + bf2f(afr[m][s][1])*wlo[s].y
                    + bf2f(afr[m][s][2])*wlo[s].z + bf2f(afr[m][s][3])*wlo[s].w
                    + bf2f(afr[m][s][4])*whi[s].x + bf2f(afr[m][s][5])*whi[s].y
                    + bf2f(afr[m][s][6])*whi[s].z + bf2f(afr[m][s][7])*whi[s].w;
            }
            up += __shfl_xor(up, 16);
            up += __shfl_xor(up, 32);
            if (lg == 0) uout[(size_t)(16*m + lr)*EE + e] = up;
        }
    }

    // ---- MFMA: 16 tiles ----
#pragma unroll
    for (int m = 0; m < 2; ++m) {
#pragma unroll
        for (int n = 0; n < 4; ++n)
            acc[m][n] = __builtin_amdgcn_mfma_f32_16x16x32_bf16(afr[m][0], bfr[n][0], acc[m][n], 0, 0, 0);
#pragma unroll
        for (int n = 0; n < 4; ++n)
            acc[m][n] = __builtin_amdgcn_mfma_f32_16x16x32_bf16(afr[m][1], bfr[n][1], acc[m][n], 0, 0, 0);
    }

    // ---- BN stats (channel == wave) ----
    float s1 = 0.f, s2 = 0.f;
#pragma unroll
    for (int m = 0; m < 2; ++m)
#pragma unroll
        for (int n = 0; n < 4; ++n)
#pragma unroll
            for (int q = 0; q < 4; ++q) { float v = acc[m][n][q]; s1 += v; s2 += v*v; }
#pragma unroll
    for (int off = 1; off < 64; off <<= 1) {
        s1 += __shfl_xor(s1, off);
        s2 += __shfl_xor(s2, off);
    }
    const float mean = s1 * (1.f/2048.f);
    const float var  = s2 * (1.f/2048.f) - mean*mean;
    const float sc = ge[e] * rsqrtf(var + EPSI);
    const float sh = be[e] - mean*sc;

    // ---- normalize + ELU on fragments ----
#pragma unroll
    for (int m = 0; m < 2; ++m)
#pragma unroll
        for (int n = 0; n < 4; ++n)
#pragma unroll
            for (int q = 0; q < 4; ++q)
                acc[m][n][q] = elu(acc[m][n][q]*sc + sh);

    // ---- epilogue ----
    if constexpr (OUTM == 0) {
        float* eout = (float*)eoutv;
        __syncthreads();                     // all fragment reads of SA done
        // fragments -> swizzled chunks: value (b=16m+4lg+q, d=16n+lr), chunk
        // c = wv*16 + 4n + (lr>>2), LDS float = b*256 + (c^(b&7))*4 + (lr&3)
#pragma unroll
        for (int m = 0; m < 2; ++m)
#pragma unroll
            for (int n = 0; n < 4; ++n)
#pragma unroll
                for (int q = 0; q < 4; ++q) {
                    const int b = 16*m + 4*lg + q;
                    const int c = wv*16 + 4*n + (lr >> 2);
                    SA[b*256 + ((c ^ (b & 7)) << 2) + (lr & 3)] = acc[m][n][q];
                }
        __syncthreads();
        // cooperative dense store: wave's 8 b-runs, 1KB contiguous per instr
#pragma unroll
        for (int r = 0; r < 8; ++r) {
            const int b = 8*wv + r;
            const f32x4 v = *reinterpret_cast<const f32x4*>(&SA[b*256 + ((l ^ (b & 7)) << 2)]);
            *reinterpret_cast<f32x4*>(eout + ((size_t)b*EE + e0)*DD + 4*l) = v;
        }
    } else {
        short* eoutp = (short*)eoutv + (size_t)e*BB*DD;
        __syncthreads();                     // all fragment reads of SA done
        float (*Z)[68] = reinterpret_cast<float (*)[68]>(&SA[wv*2176]);  // 8704B/wave
#pragma unroll
        for (int m = 0; m < 2; ++m)
#pragma unroll
            for (int n = 0; n < 4; ++n)
#pragma unroll
                for (int q = 0; q < 4; ++q)
                    Z[16*m + 4*lg + q][16*n + lr] = acc[m][n][q];
        LGKM0();
#pragma unroll
        for (int it = 0; it < 4; ++it) {
            const int rr = (l >> 3) + 8*it;  // 0..31 (batch)
            const int c0 = (l & 7)*8;
            const float4 zlo = *reinterpret_cast<const float4*>(&Z[rr][c0]);
            const float4 zhi = *reinterpret_cast<const float4*>(&Z[rr][c0+4]);
            bf16x8 o;
            o[0]=f2bf(zlo.x); o[1]=f2bf(zlo.y); o[2]=f2bf(zlo.z); o[3]=f2bf(zlo.w);
            o[4]=f2bf(zhi.x); o[5]=f2bf(zhi.y); o[6]=f2bf(zhi.z); o[7]=f2bf(zhi.w);
            *reinterpret_cast<bf16x8*>(eoutp + rr*64 + c0) = o;   // 1KB/instr
        }
    }
}

// ---------------------------------------------------------------------------
// k_attn: per (b,i): logits = lrelu(s[j] + t[i] + u[b,i*N+j]) -> softmax over j
//         agg[b,i,:] = sum_j attn_j * zh[b,j,:]
__global__ void k_attn(const float* __restrict__ sI, const float* __restrict__ tI,
                       const float* __restrict__ u, const float* __restrict__ zh,
                       float* __restrict__ agg)
{
    int blk = blockIdx.x; int b = blk >> 7, i = blk & 127;
    int l = threadIdx.x;
    __shared__ float at[NN];
    float ti = tI[blk];
    float l0 = sI[b*NN + l]      + ti + u[b*EE + i*NN + l];
    float l1 = sI[b*NN + l + 64] + ti + u[b*EE + i*NN + l + 64];
    l0 = l0 >= 0.f ? l0 : 0.01f*l0;
    l1 = l1 >= 0.f ? l1 : 0.01f*l1;
    float mx = fmaxf(l0, l1);
#pragma unroll
    for (int off = 32; off; off >>= 1) mx = fmaxf(mx, __shfl_xor(mx, off));
    float e0 = __expf(l0 - mx), e1 = __expf(l1 - mx);
    float sm = e0 + e1;
#pragma unroll
    for (int off = 32; off; off >>= 1) sm += __shfl_xor(sm, off);
    float inv = 1.f / sm;
    at[l]      = e0 * inv;
    at[l + 64] = e1 * inv;
    __syncthreads();
    float acc = 0.f;
    for (int j = 0; j < NN; ++j) acc += at[j] * zh[(b*NN + j)*DD + l];
    agg[(b*NN + i)*DD + l] = acc;
}

// ---------------------------------------------------------------------------
// k_vbn: vertex BN (channel i over b,d) + residual + ELU
__global__ void k_vbn(const float* __restrict__ agg, const float* __restrict__ xres,
                      const float* __restrict__ gv, const float* __restrict__ bv,
                      float* __restrict__ xout)
{
    int i = blockIdx.x, t = threadIdx.x;
    float vals[8];
    float s1 = 0.f, s2 = 0.f;
#pragma unroll
    for (int q = 0; q < 8; ++q) {
        int m = t + 256*q; int b = m >> 6, d = m & 63;
        float v = agg[(b*NN + i)*DD + d];
        vals[q] = v; s1 += v; s2 += v*v;
    }
#pragma unroll
    for (int off = 1; off < 64; off <<= 1) {
        s1 += __shfl_xor(s1, off);
        s2 += __shfl_xor(s2, off);
    }
    __shared__ float r1[4], r2[4];
    int wv = t >> 6;
    if ((t & 63) == 0) { r1[wv] = s1; r2[wv] = s2; }
    __syncthreads();
    s1 = r1[0] + r1[1] + r1[2] + r1[3];
    s2 = r2[0] + r2[1] + r2[2] + r2[3];
    float mean  = s1 * (1.f/2048.f);
    float var   = s2 * (1.f/2048.f) - mean*mean;
    float scale = gv[i] * rsqrtf(var + EPSI);
    float shift = bv[i] - mean*scale;
#pragma unroll
    for (int q = 0; q < 8; ++q) {
        int m = t + 256*q; int b = m >> 6, d = m & 63;
        float v = vals[q]*scale + shift + xres[(b*NN + i)*DD + d];
        xout[(b*NN + i)*DD + d] = v > 0.f ? v : __expf(v) - 1.f;
    }
}

// ---------------------------------------------------------------------------
extern "C" void kernel_launch(void* const* d_in, const int* in_sizes, int n_in,
                              void* d_out, int out_size, void* d_ws, size_t ws_size,
                              hipStream_t stream)
{
    const float* x    = (const float*)d_in[0];
    const float* edge = (const float*)d_in[1];
    const float* Wh1  = (const float*)d_in[2];
    const float* We1  = (const float*)d_in[3];
    const float* Wp1  = (const float*)d_in[4];
    const float* Wa1  = (const float*)d_in[5];
    const float* Wh2  = (const float*)d_in[6];
    const float* We2  = (const float*)d_in[7];
    const float* Wp2  = (const float*)d_in[8];
    const float* Wa2  = (const float*)d_in[9];
    const float* gv1  = (const float*)d_in[10];
    const float* bv1  = (const float*)d_in[11];
    const float* ge1  = (const float*)d_in[12];
    const float* be1  = (const float*)d_in[13];
    const float* gv2  = (const float*)d_in[14];
    const float* bv2  = (const float*)d_in[15];
    const float* ge2  = (const float*)d_in[16];
    const float* be2  = (const float*)d_in[17];

    float* xout = (float*)d_out;                    // (B,N,D)
    float* eout = (float*)d_out + BB*NN*DD;         // (B,E,D) final edge output

    float* ws  = (float*)d_ws;
    short* Mbf = (short*)ws;  ws += DD*DD/2;        // bf16 M^T (8 KB)
    float* wf  = ws;  ws += DD;                     // fp32 w
    float* zh  = ws;  ws += BB*NN*DD;
    float* PsT = ws;  ws += NN*BB*DD;               // fragment-layout Ps (1 MB)
    float* PdT = ws;  ws += NN*BB*DD;               // fragment-layout Pd (1 MB)
    float* sb  = ws;  ws += BB*NN;
    float* tb  = ws;  ws += BB*NN;
    float* ub  = ws;  ws += BB*EE;
    float* agg = ws;  ws += BB*NN*DD;
    float* x1  = ws;  ws += BB*NN*DD;
    short* e1bf = (short*)ws;                       // (E,B,D) bf16 intermediate (67 MB)
    const size_t need = ((size_t)(ws - (float*)d_ws))*4 + (size_t)EE*BB*DD*2;

    const bool dense = (ws_size >= need);

    // ----- layer 1 -----
    k_node<<<BB*NN + 64, 64, 0, stream>>>(x, Wh1, Wp1, We1, Wa1, zh, PsT, PdT, sb, tb, Mbf, wf);
    if (dense)
        k_edge<0,1><<<EE/4, 256, 0, stream>>>(edge, Mbf, wf, PsT, PdT, ge1, be1, e1bf, ub);
    else
        k_edge<0,0><<<EE/4, 256, 0, stream>>>(edge, Mbf, wf, PsT, PdT, ge1, be1, eout, ub);
    k_attn<<<BB*NN, 64, 0, stream>>>(sb, tb, ub, zh, agg);
    k_vbn<<<NN, 256, 0, stream>>>(agg, x, gv1, bv1, x1);
    // ----- layer 2 -----
    k_node<<<BB*NN + 64, 64, 0, stream>>>(x1, Wh2, Wp2, We2, Wa2, zh, PsT, PdT, sb, tb, Mbf, wf);
    if (dense)
        k_edge<1,0><<<EE/4, 256, 0, stream>>>(e1bf, Mbf, wf, PsT, PdT, ge2, be2, eout, ub);
    else  // in-place: stage reads drain at the barrier before any store
        k_edge<0,0><<<EE/4, 256, 0, stream>>>(eout, Mbf, wf, PsT, PdT, ge2, be2, eout, ub);
    k_attn<<<BB*NN, 64, 0, stream>>>(sb, tb, ub, zh, agg);
    k_vbn<<<NN, 256, 0, stream>>>(agg, x1, gv2, bv2, xout);
}